// Round 3
// baseline (757.025 us; speedup 1.0000x reference)
//
#include <hip/hip_runtime.h>

#define EPSF 1e-5f

__device__ __forceinline__ float elu_f(float x) { return x > 0.f ? x : expm1f(x); }

// ---------------- CSR build ----------------

__global__ __launch_bounds__(256) void k_zero(int* p, int n) {
    int i = blockIdx.x * 256 + threadIdx.x;
    if (i < n) p[i] = 0;
}

__global__ __launch_bounds__(256) void k_count(const int* __restrict__ dst, int* __restrict__ cnt, int E) {
    int e = blockIdx.x * 256 + threadIdx.x;
    if (e < E) atomicAdd(&cnt[dst[e]], 1);
}

#define SCAN_T 256
#define SCAN_E 4
#define SCAN_B (SCAN_T * SCAN_E)  // 1024 elems per block

__global__ __launch_bounds__(256) void k_scan1(const int* __restrict__ cnt, int* __restrict__ base,
                                               int* __restrict__ bsum, int n) {
    __shared__ int sh[SCAN_T];
    int t = threadIdx.x;
    int b0 = blockIdx.x * SCAN_B;
    int v[SCAN_E];
    int tsum = 0;
    #pragma unroll
    for (int j = 0; j < SCAN_E; ++j) {
        int idx = b0 + t * SCAN_E + j;
        v[j] = (idx < n) ? cnt[idx] : 0;
        tsum += v[j];
    }
    sh[t] = tsum;
    __syncthreads();
    for (int off = 1; off < SCAN_T; off <<= 1) {
        int add = (t >= off) ? sh[t - off] : 0;
        __syncthreads();
        sh[t] += add;
        __syncthreads();
    }
    int run = sh[t] - tsum;  // exclusive prefix of this thread
    if (t == SCAN_T - 1) bsum[blockIdx.x] = sh[t];
    #pragma unroll
    for (int j = 0; j < SCAN_E; ++j) {
        int idx = b0 + t * SCAN_E + j;
        if (idx < n) base[idx] = run;
        run += v[j];
    }
}

__global__ __launch_bounds__(256) void k_scan2(int* bsum, int nb) {
    __shared__ int sh[SCAN_T];
    int t = threadIdx.x;
    int v = (t < nb) ? bsum[t] : 0;
    sh[t] = v;
    __syncthreads();
    for (int off = 1; off < SCAN_T; off <<= 1) {
        int add = (t >= off) ? sh[t - off] : 0;
        __syncthreads();
        sh[t] += add;
        __syncthreads();
    }
    if (t < nb) bsum[t] = sh[t] - v;  // exclusive
}

__global__ __launch_bounds__(256) void k_scan3(int* base, const int* __restrict__ bsum, int n) {
    int i = blockIdx.x * 256 + threadIdx.x;
    if (i < n) base[i] += bsum[i / SCAN_B];
}

__global__ __launch_bounds__(256) void k_dinv(const int* __restrict__ cnt, float* __restrict__ dinv, int n) {
    int i = blockIdx.x * 256 + threadIdx.x;
    if (i < n) dinv[i] = rsqrtf((float)(cnt[i] + 1));  // +1 self-loop
}

__global__ __launch_bounds__(256) void k_fill(const int* __restrict__ src, const int* __restrict__ dst,
                                              const int* __restrict__ base, int* __restrict__ fcnt,
                                              const float* __restrict__ dinv,
                                              int* __restrict__ csr_src, float* __restrict__ csr_w, int E) {
    int e = blockIdx.x * 256 + threadIdx.x;
    if (e >= E) return;
    int d = dst[e];
    int s = src[e];
    int pos = base[d] + atomicAdd(&fcnt[d], 1);
    csr_src[pos] = s;
    csr_w[pos] = dinv[s];  // dinv[dst] hoisted into gather epilogue
}

// ---------------- CSR gather-aggregate ----------------
// out[i] = dinv_i * ( sum_e w_e * x[src_e] + dinv_i * x[i] )  [+ bias/BN/ELU epilogue]
template<int F, bool L1EPI>
__global__ __launch_bounds__(256) void k_gather(const int* __restrict__ base, const int* __restrict__ cnt,
                                                const int* __restrict__ csr_src, const float* __restrict__ csr_w,
                                                const float* __restrict__ dinv, const float* __restrict__ xin,
                                                const float* __restrict__ b, const float* __restrict__ g,
                                                const float* __restrict__ be, const float* __restrict__ rm,
                                                const float* __restrict__ rv, float* __restrict__ out, int n) {
    constexpr int C = F / 4;          // float4 lanes per node
    constexpr int NPB = 256 / C;      // nodes per block
    int lane = threadIdx.x % C;
    int nl = threadIdx.x / C;
    int i = blockIdx.x * NPB + nl;
    if (i >= n) return;
    int k = base[i];
    int kend = k + cnt[i];
    float di = dinv[i];
    const float4* X4 = reinterpret_cast<const float4*>(xin);
    float4 acc = {0.f, 0.f, 0.f, 0.f};
    float4 acc2 = {0.f, 0.f, 0.f, 0.f};
    for (; k + 1 < kend; k += 2) {
        int sa = csr_src[k];     float wa = csr_w[k];
        int sb = csr_src[k + 1]; float wb = csr_w[k + 1];
        float4 xa = X4[(long)sa * C + lane];
        float4 xb = X4[(long)sb * C + lane];
        acc.x += wa * xa.x; acc.y += wa * xa.y; acc.z += wa * xa.z; acc.w += wa * xa.w;
        acc2.x += wb * xb.x; acc2.y += wb * xb.y; acc2.z += wb * xb.z; acc2.w += wb * xb.w;
    }
    if (k < kend) {
        int sa = csr_src[k]; float wa = csr_w[k];
        float4 xa = X4[(long)sa * C + lane];
        acc.x += wa * xa.x; acc.y += wa * xa.y; acc.z += wa * xa.z; acc.w += wa * xa.w;
    }
    acc.x += acc2.x; acc.y += acc2.y; acc.z += acc2.z; acc.w += acc2.w;
    float4 xs = X4[(long)i * C + lane];
    float4 o;
    o.x = di * (acc.x + di * xs.x);
    o.y = di * (acc.y + di * xs.y);
    o.z = di * (acc.z + di * xs.z);
    o.w = di * (acc.w + di * xs.w);
    if (L1EPI) {
        float4 bb = reinterpret_cast<const float4*>(b)[lane];
        float4 gg = reinterpret_cast<const float4*>(g)[lane];
        float4 ee = reinterpret_cast<const float4*>(be)[lane];
        float4 mm = reinterpret_cast<const float4*>(rm)[lane];
        float4 vv = reinterpret_cast<const float4*>(rv)[lane];
        o.x = elu_f((o.x + bb.x - mm.x) * rsqrtf(vv.x + EPSF) * gg.x + ee.x);
        o.y = elu_f((o.y + bb.y - mm.y) * rsqrtf(vv.y + EPSF) * gg.y + ee.y);
        o.z = elu_f((o.z + bb.z - mm.z) * rsqrtf(vv.z + EPSF) * gg.z + ee.z);
        o.w = elu_f((o.w + bb.w - mm.w) * rsqrtf(vv.w + EPSF) * gg.w + ee.w);
    }
    reinterpret_cast<float4*>(out)[(long)i * C + lane] = o;
}

// scalar gather for layer 4 + final sigmoid(elu(.)) epilogue, writes d_out
__global__ __launch_bounds__(256) void k_gather1_final(const int* __restrict__ base, const int* __restrict__ cnt,
                                                       const int* __restrict__ csr_src, const float* __restrict__ csr_w,
                                                       const float* __restrict__ dinv, const float* __restrict__ y,
                                                       const float* __restrict__ b4, float* __restrict__ out, int n) {
    int i = blockIdx.x * 256 + threadIdx.x;
    if (i >= n) return;
    int k = base[i];
    int kend = k + cnt[i];
    float di = dinv[i];
    float acc = 0.f;
    for (; k < kend; ++k) acc += csr_w[k] * y[csr_src[k]];
    float v = di * (acc + di * y[i]) + b4[0];
    v = elu_f(v);
    out[i] = 1.f / (1.f + expf(-v));
}

// ---------------- register-tiled dense GEMM ----------------
// Thread: TR=4 rows x 4 fouts. W staged in LDS, one ds_read_b128 per k shared by 4 rows.
// Optional epilogue: bias+BN+ELU; optional fused 1-col dot (layer4 W4) with 32-lane shuffle
// reduce writing a single float per row (requires DOUT==128, block covers all fouts).
template<int DIN, int DOUT, bool BN, bool FUSE_DOT>
__global__ __launch_bounds__(256) void k_gemm_rt(const float* __restrict__ X, const float* __restrict__ W,
                                                 const float* __restrict__ b, const float* __restrict__ g,
                                                 const float* __restrict__ be, const float* __restrict__ rm,
                                                 const float* __restrict__ rv, const float* __restrict__ W4,
                                                 float* __restrict__ Y, int n) {
    constexpr int TR = 4;
    constexpr int FL = DOUT / 4;       // fout-lane groups
    constexpr int RG = 256 / FL;       // row-groups per block
    constexpr int BR = RG * TR;        // rows per block
    __shared__ float Wl[DIN * DOUT];
    for (int idx = threadIdx.x; idx < DIN * DOUT; idx += 256) Wl[idx] = W[idx];
    __syncthreads();
    const int fl = threadIdx.x % FL;
    const int rg = threadIdx.x / FL;
    const int f0 = fl * 4;
    const long r0 = (long)blockIdx.x * BR + (long)rg * TR;

    float4 z; z.x = z.y = z.z = z.w = 0.f;
    float4 acc[TR];
    #pragma unroll
    for (int r = 0; r < TR; ++r) acc[r] = z;

    #pragma unroll
    for (int k0 = 0; k0 < DIN; k0 += 4) {
        float4 xv[TR];
        #pragma unroll
        for (int r = 0; r < TR; ++r) {
            long row = r0 + r;
            xv[r] = (row < n) ? *reinterpret_cast<const float4*>(X + row * DIN + k0) : z;
        }
        #pragma unroll
        for (int kk = 0; kk < 4; ++kk) {
            float4 w4 = *reinterpret_cast<const float4*>(&Wl[(k0 + kk) * DOUT + f0]);
            #pragma unroll
            for (int r = 0; r < TR; ++r) {
                float xs = (kk == 0) ? xv[r].x : (kk == 1) ? xv[r].y : (kk == 2) ? xv[r].z : xv[r].w;
                acc[r].x += xs * w4.x;
                acc[r].y += xs * w4.y;
                acc[r].z += xs * w4.z;
                acc[r].w += xs * w4.w;
            }
        }
    }

    float4 bias = z, scale = z, shift = z, w4d = z;
    if (BN) {
        bias = *reinterpret_cast<const float4*>(b + f0);
        float4 gg = *reinterpret_cast<const float4*>(g + f0);
        float4 ee = *reinterpret_cast<const float4*>(be + f0);
        float4 mm = *reinterpret_cast<const float4*>(rm + f0);
        float4 vv = *reinterpret_cast<const float4*>(rv + f0);
        scale.x = gg.x * rsqrtf(vv.x + EPSF); shift.x = ee.x - mm.x * scale.x;
        scale.y = gg.y * rsqrtf(vv.y + EPSF); shift.y = ee.y - mm.y * scale.y;
        scale.z = gg.z * rsqrtf(vv.z + EPSF); shift.z = ee.z - mm.z * scale.z;
        scale.w = gg.w * rsqrtf(vv.w + EPSF); shift.w = ee.w - mm.w * scale.w;
    }
    if (FUSE_DOT) w4d = *reinterpret_cast<const float4*>(W4 + f0);

    #pragma unroll
    for (int r = 0; r < TR; ++r) {
        long row = r0 + r;
        if (row >= n) continue;
        float4 v = acc[r];
        if (BN) {
            v.x = elu_f((v.x + bias.x) * scale.x + shift.x);
            v.y = elu_f((v.y + bias.y) * scale.y + shift.y);
            v.z = elu_f((v.z + bias.z) * scale.z + shift.z);
            v.w = elu_f((v.w + bias.w) * scale.w + shift.w);
        }
        if (FUSE_DOT) {
            float p = v.x * w4d.x + v.y * w4d.y + v.z * w4d.z + v.w * w4d.w;
            #pragma unroll
            for (int m = 1; m < FL; m <<= 1) p += __shfl_xor(p, m, 64);
            if (fl == 0) Y[row] = p;
        } else {
            *reinterpret_cast<float4*>(Y + row * DOUT + f0) = v;
        }
    }
}

// ---------------- launch ----------------

extern "C" void kernel_launch(void* const* d_in, const int* in_sizes, int n_in,
                              void* d_out, int out_size, void* d_ws, size_t ws_size,
                              hipStream_t stream) {
    const float* x   = (const float*)d_in[0];
    const int*   edg = (const int*)d_in[1];
    const float* W1 = (const float*)d_in[2];
    const float* b1 = (const float*)d_in[3];
    const float* W2 = (const float*)d_in[4];
    const float* b2 = (const float*)d_in[5];
    const float* W3 = (const float*)d_in[6];
    const float* b3 = (const float*)d_in[7];
    const float* W4 = (const float*)d_in[8];
    const float* b4 = (const float*)d_in[9];
    const float* g1  = (const float*)d_in[10];
    const float* be1 = (const float*)d_in[11];
    const float* rm1 = (const float*)d_in[12];
    const float* rv1 = (const float*)d_in[13];
    const float* g2  = (const float*)d_in[14];
    const float* be2 = (const float*)d_in[15];
    const float* rm2 = (const float*)d_in[16];
    const float* rv2 = (const float*)d_in[17];
    const float* g3  = (const float*)d_in[18];
    const float* be3 = (const float*)d_in[19];
    const float* rm3 = (const float*)d_in[20];
    const float* rv3 = (const float*)d_in[21];
    float* out = (float*)d_out;

    const int N = in_sizes[0] / 64;
    const int E = in_sizes[1] / 2;
    const int* src = edg;
    const int* dst = edg + E;
    const int NB_SCAN = (N + SCAN_B - 1) / SCAN_B;

    // workspace layout (all 16B-aligned by construction)
    int*   cnt     = (int*)d_ws;                    // N
    int*   fcnt    = cnt + N;                       // N
    int*   base    = fcnt + N;                      // N
    int*   bsum    = base + N;                      // 256
    int*   csr_src = bsum + 256;                    // E
    float* csr_w   = (float*)(csr_src + E);         // E
    float* dinv    = csr_w + E;                     // N
    float* A       = dinv + N;                      // N*64 max
    float* B       = A + (size_t)N * 64;            // N*64 max

    auto nb = [](long total) { return (int)((total + 255) / 256); };

    // CSR build (per call: workspace re-poisoned every launch)
    k_zero<<<nb(2L * N), 256, 0, stream>>>(cnt, 2 * N);              // cnt + fcnt contiguous
    k_count<<<nb(E), 256, 0, stream>>>(dst, cnt, E);
    k_scan1<<<NB_SCAN, 256, 0, stream>>>(cnt, base, bsum, N);
    k_scan2<<<1, 256, 0, stream>>>(bsum, NB_SCAN);
    k_scan3<<<nb(N), 256, 0, stream>>>(base, bsum, N);
    k_dinv<<<nb(N), 256, 0, stream>>>(cnt, dinv, N);
    k_fill<<<nb(E), 256, 0, stream>>>(src, dst, base, fcnt, dinv, csr_src, csr_w, E);

    // Layer 1 (64->32): GEMM, then gather-agg fused with bias+BN+ELU
    k_gemm_rt<64, 32, false, false><<<(N + 127) / 128, 256, 0, stream>>>(
        x, W1, nullptr, nullptr, nullptr, nullptr, nullptr, nullptr, A, N);
    k_gather<32, true><<<(N + 31) / 32, 256, 0, stream>>>(base, cnt, csr_src, csr_w, dinv, A,
                                                          b1, g1, be1, rm1, rv1, B, N);

    // Layer 2 (32->64): gather-agg first, then fused GEMM+bias+BN+ELU
    k_gather<32, false><<<(N + 31) / 32, 256, 0, stream>>>(base, cnt, csr_src, csr_w, dinv, B,
                                                           nullptr, nullptr, nullptr, nullptr, nullptr, A, N);
    k_gemm_rt<32, 64, true, false><<<(N + 63) / 64, 256, 0, stream>>>(
        A, W2, b2, g2, be2, rm2, rv2, nullptr, B, N);

    // Layer 3 (64->128): gather-agg, then fused GEMM+bias+BN+ELU+dot(W4) -> y in B
    k_gather<64, false><<<(N + 15) / 16, 256, 0, stream>>>(base, cnt, csr_src, csr_w, dinv, B,
                                                           nullptr, nullptr, nullptr, nullptr, nullptr, A, N);
    k_gemm_rt<64, 128, true, true><<<(N + 31) / 32, 256, 0, stream>>>(
        A, W3, b3, g3, be3, rm3, rv3, W4, B, N);

    // Layer 4 (128->1): scalar gather-agg fused with bias + sigmoid(elu(.)) -> d_out
    k_gather1_final<<<nb(N), 256, 0, stream>>>(base, cnt, csr_src, csr_w, dinv, B, b4, out, N);
}

// Round 4
// 499.351 us; speedup vs baseline: 1.5160x; 1.5160x over previous
//
#include <hip/hip_runtime.h>

#define EPSF 1e-5f

__device__ __forceinline__ float elu_f(float x) { return x > 0.f ? x : expm1f(x); }

// ---------------- CSR build ----------------

__global__ __launch_bounds__(256) void k_zero(int* p, int n) {
    int i = blockIdx.x * 256 + threadIdx.x;
    if (i < n) p[i] = 0;
}

__global__ __launch_bounds__(256) void k_count(const int* __restrict__ dst, int* __restrict__ cnt, int E) {
    int e = blockIdx.x * 256 + threadIdx.x;
    if (e < E) atomicAdd(&cnt[dst[e]], 1);
}

#define SCAN_T 256
#define SCAN_E 4
#define SCAN_B (SCAN_T * SCAN_E)  // 1024 elems per block

__global__ __launch_bounds__(256) void k_scan1(const int* __restrict__ cnt, int* __restrict__ base,
                                               int* __restrict__ bsum, int n) {
    __shared__ int sh[SCAN_T];
    int t = threadIdx.x;
    int b0 = blockIdx.x * SCAN_B;
    int v[SCAN_E];
    int tsum = 0;
    #pragma unroll
    for (int j = 0; j < SCAN_E; ++j) {
        int idx = b0 + t * SCAN_E + j;
        v[j] = (idx < n) ? cnt[idx] : 0;
        tsum += v[j];
    }
    sh[t] = tsum;
    __syncthreads();
    for (int off = 1; off < SCAN_T; off <<= 1) {
        int add = (t >= off) ? sh[t - off] : 0;
        __syncthreads();
        sh[t] += add;
        __syncthreads();
    }
    int run = sh[t] - tsum;  // exclusive prefix of this thread
    if (t == SCAN_T - 1) bsum[blockIdx.x] = sh[t];
    #pragma unroll
    for (int j = 0; j < SCAN_E; ++j) {
        int idx = b0 + t * SCAN_E + j;
        if (idx < n) base[idx] = run;
        run += v[j];
    }
}

__global__ __launch_bounds__(256) void k_scan2(int* bsum, int nb) {
    __shared__ int sh[SCAN_T];
    int t = threadIdx.x;
    int v = (t < nb) ? bsum[t] : 0;
    sh[t] = v;
    __syncthreads();
    for (int off = 1; off < SCAN_T; off <<= 1) {
        int add = (t >= off) ? sh[t - off] : 0;
        __syncthreads();
        sh[t] += add;
        __syncthreads();
    }
    if (t < nb) bsum[t] = sh[t] - v;  // exclusive
}

__global__ __launch_bounds__(256) void k_scan3(int* base, const int* __restrict__ bsum, int n) {
    int i = blockIdx.x * 256 + threadIdx.x;
    if (i < n) base[i] += bsum[i / SCAN_B];
}

__global__ __launch_bounds__(256) void k_dinv(const int* __restrict__ cnt, float* __restrict__ dinv, int n) {
    int i = blockIdx.x * 256 + threadIdx.x;
    if (i < n) dinv[i] = rsqrtf((float)(cnt[i] + 1));  // +1 self-loop
}

__global__ __launch_bounds__(256) void k_fill(const int* __restrict__ src, const int* __restrict__ dst,
                                              const int* __restrict__ base, int* __restrict__ fcnt,
                                              const float* __restrict__ dinv,
                                              int* __restrict__ csr_src, float* __restrict__ csr_w, int E) {
    int e = blockIdx.x * 256 + threadIdx.x;
    if (e >= E) return;
    int d = dst[e];
    int s = src[e];
    int pos = base[d] + atomicAdd(&fcnt[d], 1);
    csr_src[pos] = s;
    csr_w[pos] = dinv[s];  // dinv[dst] hoisted into gather epilogue
}

// ---------------- CSR gather-aggregate ----------------
// out[i] = dinv_i * ( sum_e w_e * x[src_e] + dinv_i * x[i] )  [+ bias/BN/ELU epilogue]
template<int F, bool L1EPI>
__global__ __launch_bounds__(256) void k_gather(const int* __restrict__ base, const int* __restrict__ cnt,
                                                const int* __restrict__ csr_src, const float* __restrict__ csr_w,
                                                const float* __restrict__ dinv, const float* __restrict__ xin,
                                                const float* __restrict__ b, const float* __restrict__ g,
                                                const float* __restrict__ be, const float* __restrict__ rm,
                                                const float* __restrict__ rv, float* __restrict__ out, int n) {
    constexpr int C = F / 4;          // float4 lanes per node
    constexpr int NPB = 256 / C;      // nodes per block
    int lane = threadIdx.x % C;
    int nl = threadIdx.x / C;
    int i = blockIdx.x * NPB + nl;
    if (i >= n) return;
    int k = base[i];
    int kend = k + cnt[i];
    float di = dinv[i];
    const float4* X4 = reinterpret_cast<const float4*>(xin);
    float4 acc = {0.f, 0.f, 0.f, 0.f};
    float4 acc2 = {0.f, 0.f, 0.f, 0.f};
    for (; k + 1 < kend; k += 2) {
        int sa = csr_src[k];     float wa = csr_w[k];
        int sb = csr_src[k + 1]; float wb = csr_w[k + 1];
        float4 xa = X4[(long)sa * C + lane];
        float4 xb = X4[(long)sb * C + lane];
        acc.x += wa * xa.x; acc.y += wa * xa.y; acc.z += wa * xa.z; acc.w += wa * xa.w;
        acc2.x += wb * xb.x; acc2.y += wb * xb.y; acc2.z += wb * xb.z; acc2.w += wb * xb.w;
    }
    if (k < kend) {
        int sa = csr_src[k]; float wa = csr_w[k];
        float4 xa = X4[(long)sa * C + lane];
        acc.x += wa * xa.x; acc.y += wa * xa.y; acc.z += wa * xa.z; acc.w += wa * xa.w;
    }
    acc.x += acc2.x; acc.y += acc2.y; acc.z += acc2.z; acc.w += acc2.w;
    float4 xs = X4[(long)i * C + lane];
    float4 o;
    o.x = di * (acc.x + di * xs.x);
    o.y = di * (acc.y + di * xs.y);
    o.z = di * (acc.z + di * xs.z);
    o.w = di * (acc.w + di * xs.w);
    if (L1EPI) {
        float4 bb = reinterpret_cast<const float4*>(b)[lane];
        float4 gg = reinterpret_cast<const float4*>(g)[lane];
        float4 ee = reinterpret_cast<const float4*>(be)[lane];
        float4 mm = reinterpret_cast<const float4*>(rm)[lane];
        float4 vv = reinterpret_cast<const float4*>(rv)[lane];
        o.x = elu_f((o.x + bb.x - mm.x) * rsqrtf(vv.x + EPSF) * gg.x + ee.x);
        o.y = elu_f((o.y + bb.y - mm.y) * rsqrtf(vv.y + EPSF) * gg.y + ee.y);
        o.z = elu_f((o.z + bb.z - mm.z) * rsqrtf(vv.z + EPSF) * gg.z + ee.z);
        o.w = elu_f((o.w + bb.w - mm.w) * rsqrtf(vv.w + EPSF) * gg.w + ee.w);
    }
    reinterpret_cast<float4*>(out)[(long)i * C + lane] = o;
}

// scalar gather for layer 4 + final sigmoid(elu(.)) epilogue, writes d_out
__global__ __launch_bounds__(256) void k_gather1_final(const int* __restrict__ base, const int* __restrict__ cnt,
                                                       const int* __restrict__ csr_src, const float* __restrict__ csr_w,
                                                       const float* __restrict__ dinv, const float* __restrict__ y,
                                                       const float* __restrict__ b4, float* __restrict__ out, int n) {
    int i = blockIdx.x * 256 + threadIdx.x;
    if (i >= n) return;
    int k = base[i];
    int kend = k + cnt[i];
    float di = dinv[i];
    float acc = 0.f;
    for (; k < kend; ++k) acc += csr_w[k] * y[csr_src[k]];
    float v = di * (acc + di * y[i]) + b4[0];
    v = elu_f(v);
    out[i] = 1.f / (1.f + expf(-v));
}

// ---------------- register-tiled dense GEMM ----------------
// Thread: TR=4 rows x 4 fouts. W staged in LDS, one ds_read_b128 per k shared by 4 rows.
// __launch_bounds__(256,4): cap VGPR at 128 so >=4 waves/SIMD (R3 lesson: full unroll
// hoisted 256 floats of X loads -> 256 VGPR -> 10.9% occupancy -> latency-exposed).
// #pragma unroll 2 keeps only 2 k0-iterations of X loads in flight.
template<int DIN, int DOUT, bool BN, bool FUSE_DOT>
__global__ __launch_bounds__(256, 4) void k_gemm_rt(const float* __restrict__ X, const float* __restrict__ W,
                                                    const float* __restrict__ b, const float* __restrict__ g,
                                                    const float* __restrict__ be, const float* __restrict__ rm,
                                                    const float* __restrict__ rv, const float* __restrict__ W4,
                                                    float* __restrict__ Y, int n) {
    constexpr int TR = 4;
    constexpr int FL = DOUT / 4;       // fout-lane groups
    constexpr int RG = 256 / FL;       // row-groups per block
    constexpr int BR = RG * TR;        // rows per block
    __shared__ float Wl[DIN * DOUT];
    for (int idx = threadIdx.x; idx < DIN * DOUT; idx += 256) Wl[idx] = W[idx];
    __syncthreads();
    const int fl = threadIdx.x % FL;
    const int rg = threadIdx.x / FL;
    const int f0 = fl * 4;
    const long r0 = (long)blockIdx.x * BR + (long)rg * TR;

    float4 z; z.x = z.y = z.z = z.w = 0.f;
    float4 acc[TR];
    #pragma unroll
    for (int r = 0; r < TR; ++r) acc[r] = z;

    #pragma unroll 2
    for (int k0 = 0; k0 < DIN; k0 += 4) {
        float4 xv[TR];
        #pragma unroll
        for (int r = 0; r < TR; ++r) {
            long row = r0 + r;
            xv[r] = (row < n) ? *reinterpret_cast<const float4*>(X + row * DIN + k0) : z;
        }
        #pragma unroll
        for (int kk = 0; kk < 4; ++kk) {
            float4 w4 = *reinterpret_cast<const float4*>(&Wl[(k0 + kk) * DOUT + f0]);
            #pragma unroll
            for (int r = 0; r < TR; ++r) {
                float xs = (kk == 0) ? xv[r].x : (kk == 1) ? xv[r].y : (kk == 2) ? xv[r].z : xv[r].w;
                acc[r].x += xs * w4.x;
                acc[r].y += xs * w4.y;
                acc[r].z += xs * w4.z;
                acc[r].w += xs * w4.w;
            }
        }
    }

    float4 bias = z, scale = z, shift = z, w4d = z;
    if (BN) {
        bias = *reinterpret_cast<const float4*>(b + f0);
        float4 gg = *reinterpret_cast<const float4*>(g + f0);
        float4 ee = *reinterpret_cast<const float4*>(be + f0);
        float4 mm = *reinterpret_cast<const float4*>(rm + f0);
        float4 vv = *reinterpret_cast<const float4*>(rv + f0);
        scale.x = gg.x * rsqrtf(vv.x + EPSF); shift.x = ee.x - mm.x * scale.x;
        scale.y = gg.y * rsqrtf(vv.y + EPSF); shift.y = ee.y - mm.y * scale.y;
        scale.z = gg.z * rsqrtf(vv.z + EPSF); shift.z = ee.z - mm.z * scale.z;
        scale.w = gg.w * rsqrtf(vv.w + EPSF); shift.w = ee.w - mm.w * scale.w;
    }
    if (FUSE_DOT) w4d = *reinterpret_cast<const float4*>(W4 + f0);

    #pragma unroll
    for (int r = 0; r < TR; ++r) {
        long row = r0 + r;
        if (row >= n) continue;
        float4 v = acc[r];
        if (BN) {
            v.x = elu_f((v.x + bias.x) * scale.x + shift.x);
            v.y = elu_f((v.y + bias.y) * scale.y + shift.y);
            v.z = elu_f((v.z + bias.z) * scale.z + shift.z);
            v.w = elu_f((v.w + bias.w) * scale.w + shift.w);
        }
        if (FUSE_DOT) {
            float p = v.x * w4d.x + v.y * w4d.y + v.z * w4d.z + v.w * w4d.w;
            #pragma unroll
            for (int m = 1; m < FL; m <<= 1) p += __shfl_xor(p, m, 64);
            if (fl == 0) Y[row] = p;
        } else {
            *reinterpret_cast<float4*>(Y + row * DOUT + f0) = v;
        }
    }
}

// ---------------- launch ----------------

extern "C" void kernel_launch(void* const* d_in, const int* in_sizes, int n_in,
                              void* d_out, int out_size, void* d_ws, size_t ws_size,
                              hipStream_t stream) {
    const float* x   = (const float*)d_in[0];
    const int*   edg = (const int*)d_in[1];
    const float* W1 = (const float*)d_in[2];
    const float* b1 = (const float*)d_in[3];
    const float* W2 = (const float*)d_in[4];
    const float* b2 = (const float*)d_in[5];
    const float* W3 = (const float*)d_in[6];
    const float* b3 = (const float*)d_in[7];
    const float* W4 = (const float*)d_in[8];
    const float* b4 = (const float*)d_in[9];
    const float* g1  = (const float*)d_in[10];
    const float* be1 = (const float*)d_in[11];
    const float* rm1 = (const float*)d_in[12];
    const float* rv1 = (const float*)d_in[13];
    const float* g2  = (const float*)d_in[14];
    const float* be2 = (const float*)d_in[15];
    const float* rm2 = (const float*)d_in[16];
    const float* rv2 = (const float*)d_in[17];
    const float* g3  = (const float*)d_in[18];
    const float* be3 = (const float*)d_in[19];
    const float* rm3 = (const float*)d_in[20];
    const float* rv3 = (const float*)d_in[21];
    float* out = (float*)d_out;

    const int N = in_sizes[0] / 64;
    const int E = in_sizes[1] / 2;
    const int* src = edg;
    const int* dst = edg + E;
    const int NB_SCAN = (N + SCAN_B - 1) / SCAN_B;

    // workspace layout (all 16B-aligned by construction)
    int*   cnt     = (int*)d_ws;                    // N
    int*   fcnt    = cnt + N;                       // N
    int*   base    = fcnt + N;                      // N
    int*   bsum    = base + N;                      // 256
    int*   csr_src = bsum + 256;                    // E
    float* csr_w   = (float*)(csr_src + E);         // E
    float* dinv    = csr_w + E;                     // N
    float* A       = dinv + N;                      // N*64 max
    float* B       = A + (size_t)N * 64;            // N*64 max

    auto nb = [](long total) { return (int)((total + 255) / 256); };

    // CSR build (per call: workspace re-poisoned every launch)
    k_zero<<<nb(2L * N), 256, 0, stream>>>(cnt, 2 * N);              // cnt + fcnt contiguous
    k_count<<<nb(E), 256, 0, stream>>>(dst, cnt, E);
    k_scan1<<<NB_SCAN, 256, 0, stream>>>(cnt, base, bsum, N);
    k_scan2<<<1, 256, 0, stream>>>(bsum, NB_SCAN);
    k_scan3<<<nb(N), 256, 0, stream>>>(base, bsum, N);
    k_dinv<<<nb(N), 256, 0, stream>>>(cnt, dinv, N);
    k_fill<<<nb(E), 256, 0, stream>>>(src, dst, base, fcnt, dinv, csr_src, csr_w, E);

    // Layer 1 (64->32): GEMM, then gather-agg fused with bias+BN+ELU
    k_gemm_rt<64, 32, false, false><<<(N + 127) / 128, 256, 0, stream>>>(
        x, W1, nullptr, nullptr, nullptr, nullptr, nullptr, nullptr, A, N);
    k_gather<32, true><<<(N + 31) / 32, 256, 0, stream>>>(base, cnt, csr_src, csr_w, dinv, A,
                                                          b1, g1, be1, rm1, rv1, B, N);

    // Layer 2 (32->64): gather-agg first, then fused GEMM+bias+BN+ELU
    k_gather<32, false><<<(N + 31) / 32, 256, 0, stream>>>(base, cnt, csr_src, csr_w, dinv, B,
                                                           nullptr, nullptr, nullptr, nullptr, nullptr, A, N);
    k_gemm_rt<32, 64, true, false><<<(N + 63) / 64, 256, 0, stream>>>(
        A, W2, b2, g2, be2, rm2, rv2, nullptr, B, N);

    // Layer 3 (64->128): gather-agg, then fused GEMM+bias+BN+ELU+dot(W4) -> y in B
    k_gather<64, false><<<(N + 15) / 16, 256, 0, stream>>>(base, cnt, csr_src, csr_w, dinv, B,
                                                           nullptr, nullptr, nullptr, nullptr, nullptr, A, N);
    k_gemm_rt<64, 128, true, true><<<(N + 31) / 32, 256, 0, stream>>>(
        A, W3, b3, g3, be3, rm3, rv3, W4, B, N);

    // Layer 4 (128->1): scalar gather-agg fused with bias + sigmoid(elu(.)) -> d_out
    k_gather1_final<<<nb(N), 256, 0, stream>>>(base, cnt, csr_src, csr_w, dinv, B, b4, out, N);
}

// Round 5
// 495.077 us; speedup vs baseline: 1.5291x; 1.0086x over previous
//
#include <hip/hip_runtime.h>

#define EPSF 1e-5f

__device__ __forceinline__ float elu_f(float x) { return x > 0.f ? x : expm1f(x); }

// ---------------- CSR build ----------------

__global__ __launch_bounds__(256) void k_zero(int* p, int n) {
    int i = blockIdx.x * 256 + threadIdx.x;
    if (i < n) p[i] = 0;
}

__global__ __launch_bounds__(256) void k_count(const int* __restrict__ dst, int* __restrict__ cnt, int E) {
    int e = blockIdx.x * 256 + threadIdx.x;
    if (e < E) atomicAdd(&cnt[dst[e]], 1);
}

#define SCAN_T 256
#define SCAN_E 4
#define SCAN_B (SCAN_T * SCAN_E)  // 1024 elems per block

// scan over cnt -> base (block-local), block sums -> bsum; also dinv = rsqrt(cnt+1)
__global__ __launch_bounds__(256) void k_scan1(const int* __restrict__ cnt, int* __restrict__ base,
                                               int* __restrict__ bsum, float* __restrict__ dinv, int n) {
    __shared__ int sh[SCAN_T];
    int t = threadIdx.x;
    int b0 = blockIdx.x * SCAN_B;
    int v[SCAN_E];
    int tsum = 0;
    #pragma unroll
    for (int j = 0; j < SCAN_E; ++j) {
        int idx = b0 + t * SCAN_E + j;
        v[j] = (idx < n) ? cnt[idx] : 0;
        if (idx < n) dinv[idx] = rsqrtf((float)(v[j] + 1));  // +1 self-loop
        tsum += v[j];
    }
    sh[t] = tsum;
    __syncthreads();
    for (int off = 1; off < SCAN_T; off <<= 1) {
        int add = (t >= off) ? sh[t - off] : 0;
        __syncthreads();
        sh[t] += add;
        __syncthreads();
    }
    int run = sh[t] - tsum;  // exclusive prefix of this thread
    if (t == SCAN_T - 1) bsum[blockIdx.x] = sh[t];
    #pragma unroll
    for (int j = 0; j < SCAN_E; ++j) {
        int idx = b0 + t * SCAN_E + j;
        if (idx < n) base[idx] = run;
        run += v[j];
    }
}

__global__ __launch_bounds__(256) void k_scan2(int* bsum, int nb) {
    __shared__ int sh[SCAN_T];
    int t = threadIdx.x;
    int v = (t < nb) ? bsum[t] : 0;
    sh[t] = v;
    __syncthreads();
    for (int off = 1; off < SCAN_T; off <<= 1) {
        int add = (t >= off) ? sh[t - off] : 0;
        __syncthreads();
        sh[t] += add;
        __syncthreads();
    }
    if (t < nb) bsum[t] = sh[t] - v;  // exclusive
}

__global__ __launch_bounds__(256) void k_scan3(int* base, const int* __restrict__ bsum, int n) {
    int i = blockIdx.x * 256 + threadIdx.x;
    if (i < n) base[i] += bsum[i / SCAN_B];
}

// packed fill: one 8B scattered write per edge (src, dinv[src]) — halves dirty-line footprint
__global__ __launch_bounds__(256) void k_fill(const int* __restrict__ src, const int* __restrict__ dst,
                                              const int* __restrict__ base, int* __restrict__ fcnt,
                                              const float* __restrict__ dinv,
                                              int2* __restrict__ csr_sw, int E) {
    int e = blockIdx.x * 256 + threadIdx.x;
    if (e >= E) return;
    int d = dst[e];
    int s = src[e];
    int pos = base[d] + atomicAdd(&fcnt[d], 1);
    int2 sw;
    sw.x = s;
    sw.y = __float_as_int(dinv[s]);  // dinv[dst] hoisted into gather epilogue
    csr_sw[pos] = sw;
}

// ---------------- CSR gather-aggregate ----------------
// out[i] = dinv_i * ( sum_e w_e * x[src_e] + dinv_i * x[i] )  [+ bias/BN/ELU epilogue]
template<int F, bool L1EPI>
__global__ __launch_bounds__(256) void k_gather(const int* __restrict__ base, const int* __restrict__ cnt,
                                                const int2* __restrict__ csr_sw,
                                                const float* __restrict__ dinv, const float* __restrict__ xin,
                                                const float* __restrict__ b, const float* __restrict__ g,
                                                const float* __restrict__ be, const float* __restrict__ rm,
                                                const float* __restrict__ rv, float* __restrict__ out, int n) {
    constexpr int C = F / 4;          // float4 lanes per node
    constexpr int NPB = 256 / C;      // nodes per block
    int lane = threadIdx.x % C;
    int nl = threadIdx.x / C;
    int i = blockIdx.x * NPB + nl;
    if (i >= n) return;
    int k = base[i];
    int kend = k + cnt[i];
    float di = dinv[i];
    const float4* X4 = reinterpret_cast<const float4*>(xin);
    float4 acc = {0.f, 0.f, 0.f, 0.f};
    float4 acc2 = {0.f, 0.f, 0.f, 0.f};
    for (; k + 1 < kend; k += 2) {
        int2 ea = csr_sw[k];
        int2 eb = csr_sw[k + 1];
        float wa = __int_as_float(ea.y);
        float wb = __int_as_float(eb.y);
        float4 xa = X4[(long)ea.x * C + lane];
        float4 xb = X4[(long)eb.x * C + lane];
        acc.x += wa * xa.x; acc.y += wa * xa.y; acc.z += wa * xa.z; acc.w += wa * xa.w;
        acc2.x += wb * xb.x; acc2.y += wb * xb.y; acc2.z += wb * xb.z; acc2.w += wb * xb.w;
    }
    if (k < kend) {
        int2 ea = csr_sw[k];
        float wa = __int_as_float(ea.y);
        float4 xa = X4[(long)ea.x * C + lane];
        acc.x += wa * xa.x; acc.y += wa * xa.y; acc.z += wa * xa.z; acc.w += wa * xa.w;
    }
    acc.x += acc2.x; acc.y += acc2.y; acc.z += acc2.z; acc.w += acc2.w;
    float4 xs = X4[(long)i * C + lane];
    float4 o;
    o.x = di * (acc.x + di * xs.x);
    o.y = di * (acc.y + di * xs.y);
    o.z = di * (acc.z + di * xs.z);
    o.w = di * (acc.w + di * xs.w);
    if (L1EPI) {
        float4 bb = reinterpret_cast<const float4*>(b)[lane];
        float4 gg = reinterpret_cast<const float4*>(g)[lane];
        float4 ee = reinterpret_cast<const float4*>(be)[lane];
        float4 mm = reinterpret_cast<const float4*>(rm)[lane];
        float4 vv = reinterpret_cast<const float4*>(rv)[lane];
        o.x = elu_f((o.x + bb.x - mm.x) * rsqrtf(vv.x + EPSF) * gg.x + ee.x);
        o.y = elu_f((o.y + bb.y - mm.y) * rsqrtf(vv.y + EPSF) * gg.y + ee.y);
        o.z = elu_f((o.z + bb.z - mm.z) * rsqrtf(vv.z + EPSF) * gg.z + ee.z);
        o.w = elu_f((o.w + bb.w - mm.w) * rsqrtf(vv.w + EPSF) * gg.w + ee.w);
    }
    reinterpret_cast<float4*>(out)[(long)i * C + lane] = o;
}

// scalar gather for layer 4 + final sigmoid(elu(.)) epilogue, writes d_out
__global__ __launch_bounds__(256) void k_gather1_final(const int* __restrict__ base, const int* __restrict__ cnt,
                                                       const int2* __restrict__ csr_sw,
                                                       const float* __restrict__ dinv, const float* __restrict__ y,
                                                       const float* __restrict__ b4, float* __restrict__ out, int n) {
    int i = blockIdx.x * 256 + threadIdx.x;
    if (i >= n) return;
    int k = base[i];
    int kend = k + cnt[i];
    float di = dinv[i];
    float acc = 0.f;
    for (; k < kend; ++k) {
        int2 ea = csr_sw[k];
        acc += __int_as_float(ea.y) * y[ea.x];
    }
    float v = di * (acc + di * y[i]) + b4[0];
    v = elu_f(v);
    out[i] = 1.f / (1.f + expf(-v));
}

// ---------------- register-tiled dense GEMM ----------------
// Thread: TR=4 rows x 4 fouts. W staged in LDS, one ds_read_b128 per k shared by 4 rows.
// __launch_bounds__(256,4): cap VGPR at 128 so >=4 waves/SIMD (R3 lesson: full unroll
// hoisted 256 floats of X loads -> 256 VGPR -> 10.9% occupancy -> latency-exposed).
// #pragma unroll 2 keeps only 2 k0-iterations of X loads in flight.
template<int DIN, int DOUT, bool BN, bool FUSE_DOT>
__global__ __launch_bounds__(256, 4) void k_gemm_rt(const float* __restrict__ X, const float* __restrict__ W,
                                                    const float* __restrict__ b, const float* __restrict__ g,
                                                    const float* __restrict__ be, const float* __restrict__ rm,
                                                    const float* __restrict__ rv, const float* __restrict__ W4,
                                                    float* __restrict__ Y, int n) {
    constexpr int TR = 4;
    constexpr int FL = DOUT / 4;       // fout-lane groups
    constexpr int RG = 256 / FL;       // row-groups per block
    constexpr int BR = RG * TR;        // rows per block
    __shared__ float Wl[DIN * DOUT];
    for (int idx = threadIdx.x; idx < DIN * DOUT; idx += 256) Wl[idx] = W[idx];
    __syncthreads();
    const int fl = threadIdx.x % FL;
    const int rg = threadIdx.x / FL;
    const int f0 = fl * 4;
    const long r0 = (long)blockIdx.x * BR + (long)rg * TR;

    float4 z; z.x = z.y = z.z = z.w = 0.f;
    float4 acc[TR];
    #pragma unroll
    for (int r = 0; r < TR; ++r) acc[r] = z;

    #pragma unroll 2
    for (int k0 = 0; k0 < DIN; k0 += 4) {
        float4 xv[TR];
        #pragma unroll
        for (int r = 0; r < TR; ++r) {
            long row = r0 + r;
            xv[r] = (row < n) ? *reinterpret_cast<const float4*>(X + row * DIN + k0) : z;
        }
        #pragma unroll
        for (int kk = 0; kk < 4; ++kk) {
            float4 w4 = *reinterpret_cast<const float4*>(&Wl[(k0 + kk) * DOUT + f0]);
            #pragma unroll
            for (int r = 0; r < TR; ++r) {
                float xs = (kk == 0) ? xv[r].x : (kk == 1) ? xv[r].y : (kk == 2) ? xv[r].z : xv[r].w;
                acc[r].x += xs * w4.x;
                acc[r].y += xs * w4.y;
                acc[r].z += xs * w4.z;
                acc[r].w += xs * w4.w;
            }
        }
    }

    float4 bias = z, scale = z, shift = z, w4d = z;
    if (BN) {
        bias = *reinterpret_cast<const float4*>(b + f0);
        float4 gg = *reinterpret_cast<const float4*>(g + f0);
        float4 ee = *reinterpret_cast<const float4*>(be + f0);
        float4 mm = *reinterpret_cast<const float4*>(rm + f0);
        float4 vv = *reinterpret_cast<const float4*>(rv + f0);
        scale.x = gg.x * rsqrtf(vv.x + EPSF); shift.x = ee.x - mm.x * scale.x;
        scale.y = gg.y * rsqrtf(vv.y + EPSF); shift.y = ee.y - mm.y * scale.y;
        scale.z = gg.z * rsqrtf(vv.z + EPSF); shift.z = ee.z - mm.z * scale.z;
        scale.w = gg.w * rsqrtf(vv.w + EPSF); shift.w = ee.w - mm.w * scale.w;
    }
    if (FUSE_DOT) w4d = *reinterpret_cast<const float4*>(W4 + f0);

    #pragma unroll
    for (int r = 0; r < TR; ++r) {
        long row = r0 + r;
        if (row >= n) continue;
        float4 v = acc[r];
        if (BN) {
            v.x = elu_f((v.x + bias.x) * scale.x + shift.x);
            v.y = elu_f((v.y + bias.y) * scale.y + shift.y);
            v.z = elu_f((v.z + bias.z) * scale.z + shift.z);
            v.w = elu_f((v.w + bias.w) * scale.w + shift.w);
        }
        if (FUSE_DOT) {
            float p = v.x * w4d.x + v.y * w4d.y + v.z * w4d.z + v.w * w4d.w;
            #pragma unroll
            for (int m = 1; m < FL; m <<= 1) p += __shfl_xor(p, m, 64);
            if (fl == 0) Y[row] = p;
        } else {
            *reinterpret_cast<float4*>(Y + row * DOUT + f0) = v;
        }
    }
}

// ---------------- launch ----------------

extern "C" void kernel_launch(void* const* d_in, const int* in_sizes, int n_in,
                              void* d_out, int out_size, void* d_ws, size_t ws_size,
                              hipStream_t stream) {
    const float* x   = (const float*)d_in[0];
    const int*   edg = (const int*)d_in[1];
    const float* W1 = (const float*)d_in[2];
    const float* b1 = (const float*)d_in[3];
    const float* W2 = (const float*)d_in[4];
    const float* b2 = (const float*)d_in[5];
    const float* W3 = (const float*)d_in[6];
    const float* b3 = (const float*)d_in[7];
    const float* W4 = (const float*)d_in[8];
    const float* b4 = (const float*)d_in[9];
    const float* g1  = (const float*)d_in[10];
    const float* be1 = (const float*)d_in[11];
    const float* rm1 = (const float*)d_in[12];
    const float* rv1 = (const float*)d_in[13];
    const float* g2  = (const float*)d_in[14];
    const float* be2 = (const float*)d_in[15];
    const float* rm2 = (const float*)d_in[16];
    const float* rv2 = (const float*)d_in[17];
    const float* g3  = (const float*)d_in[18];
    const float* be3 = (const float*)d_in[19];
    const float* rm3 = (const float*)d_in[20];
    const float* rv3 = (const float*)d_in[21];
    float* out = (float*)d_out;

    const int N = in_sizes[0] / 64;
    const int E = in_sizes[1] / 2;
    const int* src = edg;
    const int* dst = edg + E;
    const int NB_SCAN = (N + SCAN_B - 1) / SCAN_B;

    // workspace layout (all 16B-aligned by construction)
    int*   cnt     = (int*)d_ws;                    // N
    int*   fcnt    = cnt + N;                       // N
    int*   base    = fcnt + N;                      // N
    int*   bsum    = base + N;                      // 256
    int2*  csr_sw  = (int2*)(bsum + 256);           // E int2 (8B-aligned: offset 3N+256 ints, N even)
    float* dinv    = (float*)(csr_sw + E);          // N
    float* A       = dinv + N;                      // N*64 max
    float* B       = A + (size_t)N * 64;            // N*128 max... (N*64 used)

    auto nb = [](long total) { return (int)((total + 255) / 256); };

    // CSR build (per call: workspace re-poisoned every launch)
    k_zero<<<nb(2L * N), 256, 0, stream>>>(cnt, 2 * N);              // cnt + fcnt contiguous
    k_count<<<nb(E), 256, 0, stream>>>(dst, cnt, E);
    k_scan1<<<NB_SCAN, 256, 0, stream>>>(cnt, base, bsum, dinv, N);
    k_scan2<<<1, 256, 0, stream>>>(bsum, NB_SCAN);
    k_scan3<<<nb(N), 256, 0, stream>>>(base, bsum, N);
    k_fill<<<nb(E), 256, 0, stream>>>(src, dst, base, fcnt, dinv, csr_sw, E);

    // Layer 1 (64->32): GEMM, then gather-agg fused with bias+BN+ELU
    k_gemm_rt<64, 32, false, false><<<(N + 127) / 128, 256, 0, stream>>>(
        x, W1, nullptr, nullptr, nullptr, nullptr, nullptr, nullptr, A, N);
    k_gather<32, true><<<(N + 31) / 32, 256, 0, stream>>>(base, cnt, csr_sw, dinv, A,
                                                          b1, g1, be1, rm1, rv1, B, N);

    // Layer 2 (32->64): gather-agg first, then fused GEMM+bias+BN+ELU
    k_gather<32, false><<<(N + 31) / 32, 256, 0, stream>>>(base, cnt, csr_sw, dinv, B,
                                                           nullptr, nullptr, nullptr, nullptr, nullptr, A, N);
    k_gemm_rt<32, 64, true, false><<<(N + 63) / 64, 256, 0, stream>>>(
        A, W2, b2, g2, be2, rm2, rv2, nullptr, B, N);

    // Layer 3 (64->128): gather-agg, then fused GEMM+bias+BN+ELU+dot(W4) -> y in B
    k_gather<64, false><<<(N + 15) / 16, 256, 0, stream>>>(base, cnt, csr_sw, dinv, B,
                                                           nullptr, nullptr, nullptr, nullptr, nullptr, A, N);
    k_gemm_rt<64, 128, true, true><<<(N + 31) / 32, 256, 0, stream>>>(
        A, W3, b3, g3, be3, rm3, rv3, W4, B, N);

    // Layer 4 (128->1): scalar gather-agg fused with bias + sigmoid(elu(.)) -> d_out
    k_gather1_final<<<nb(N), 256, 0, stream>>>(base, cnt, csr_sw, dinv, B, b4, out, N);
}

// Round 6
// 494.814 us; speedup vs baseline: 1.5299x; 1.0005x over previous
//
#include <hip/hip_runtime.h>

#define EPSF 1e-5f

__device__ __forceinline__ float elu_f(float x) { return x > 0.f ? x : expm1f(x); }

// ---------------- CSR build ----------------

__global__ __launch_bounds__(256) void k_zero(int* p, int n) {
    int i = blockIdx.x * 256 + threadIdx.x;
    if (i < n) p[i] = 0;
}

// XCD-range-partitioned count: group g = blockIdx&7 (round-robin XCD heuristic) owns
// dst range [g*N8, g*N8+N8). Atomics stay XCD-local -> no cross-XCD L2 line bouncing.
// Correctness does not depend on the blockIdx->XCD mapping (each edge counted once).
__global__ __launch_bounds__(256) void k_count_x(const int* __restrict__ dst, int* __restrict__ cnt,
                                                 int E, int N) {
    int g = blockIdx.x & 7;
    int cb = blockIdx.x >> 3;
    int nch = gridDim.x >> 3;
    int N8 = (N + 7) >> 3;
    int lo = g * N8;
    int hi = min(N, lo + N8);
    for (long e = (long)cb * 256 + threadIdx.x; e < E; e += (long)nch * 256) {
        int d = dst[e];
        if (d >= lo && d < hi) atomicAdd(&cnt[d], 1);
    }
}

#define SCAN_T 256
#define SCAN_E 4
#define SCAN_B (SCAN_T * SCAN_E)  // 1024 elems per block

// scan over cnt -> base (block-local), block sums -> bsum; also dinv = rsqrt(cnt+1)
__global__ __launch_bounds__(256) void k_scan1(const int* __restrict__ cnt, int* __restrict__ base,
                                               int* __restrict__ bsum, float* __restrict__ dinv, int n) {
    __shared__ int sh[SCAN_T];
    int t = threadIdx.x;
    int b0 = blockIdx.x * SCAN_B;
    int v[SCAN_E];
    int tsum = 0;
    #pragma unroll
    for (int j = 0; j < SCAN_E; ++j) {
        int idx = b0 + t * SCAN_E + j;
        v[j] = (idx < n) ? cnt[idx] : 0;
        if (idx < n) dinv[idx] = rsqrtf((float)(v[j] + 1));  // +1 self-loop
        tsum += v[j];
    }
    sh[t] = tsum;
    __syncthreads();
    for (int off = 1; off < SCAN_T; off <<= 1) {
        int add = (t >= off) ? sh[t - off] : 0;
        __syncthreads();
        sh[t] += add;
        __syncthreads();
    }
    int run = sh[t] - tsum;  // exclusive prefix of this thread
    if (t == SCAN_T - 1) bsum[blockIdx.x] = sh[t];
    #pragma unroll
    for (int j = 0; j < SCAN_E; ++j) {
        int idx = b0 + t * SCAN_E + j;
        if (idx < n) base[idx] = run;
        run += v[j];
    }
}

__global__ __launch_bounds__(256) void k_scan2(int* bsum, int nb) {
    __shared__ int sh[SCAN_T];
    int t = threadIdx.x;
    int v = (t < nb) ? bsum[t] : 0;
    sh[t] = v;
    __syncthreads();
    for (int off = 1; off < SCAN_T; off <<= 1) {
        int add = (t >= off) ? sh[t - off] : 0;
        __syncthreads();
        sh[t] += add;
        __syncthreads();
    }
    if (t < nb) bsum[t] = sh[t] - v;  // exclusive
}

// finalize base and seed fcnt = base (fill then uses atomicAdd(&fcnt[d],1) directly,
// saving one scattered base[d] read per edge)
__global__ __launch_bounds__(256) void k_scan3(int* base, int* fcnt, const int* __restrict__ bsum, int n) {
    int i = blockIdx.x * 256 + threadIdx.x;
    if (i < n) {
        int v = base[i] + bsum[i / SCAN_B];
        base[i] = v;
        fcnt[i] = v;
    }
}

// XCD-range-partitioned packed fill: one 8B scattered write per edge (src, dinv[src]),
// scatter targets XCD-local per the blockIdx&7 heuristic.
__global__ __launch_bounds__(256) void k_fill_x(const int* __restrict__ src, const int* __restrict__ dst,
                                                int* __restrict__ fcnt, const float* __restrict__ dinv,
                                                int2* __restrict__ csr_sw, int E, int N) {
    int g = blockIdx.x & 7;
    int cb = blockIdx.x >> 3;
    int nch = gridDim.x >> 3;
    int N8 = (N + 7) >> 3;
    int lo = g * N8;
    int hi = min(N, lo + N8);
    for (long e = (long)cb * 256 + threadIdx.x; e < E; e += (long)nch * 256) {
        int d = dst[e];
        if (d >= lo && d < hi) {
            int s = src[e];
            int pos = atomicAdd(&fcnt[d], 1);
            int2 sw;
            sw.x = s;
            sw.y = __float_as_int(dinv[s]);  // dinv[dst] hoisted into gather epilogue
            csr_sw[pos] = sw;
        }
    }
}

// ---------------- CSR gather-aggregate ----------------
// out[i] = dinv_i * ( sum_e w_e * x[src_e] + dinv_i * x[i] )  [+ bias/BN/ELU epilogue]
template<int F, bool L1EPI>
__global__ __launch_bounds__(256) void k_gather(const int* __restrict__ base, const int* __restrict__ cnt,
                                                const int2* __restrict__ csr_sw,
                                                const float* __restrict__ dinv, const float* __restrict__ xin,
                                                const float* __restrict__ b, const float* __restrict__ g,
                                                const float* __restrict__ be, const float* __restrict__ rm,
                                                const float* __restrict__ rv, float* __restrict__ out, int n) {
    constexpr int C = F / 4;          // float4 lanes per node
    constexpr int NPB = 256 / C;      // nodes per block
    int lane = threadIdx.x % C;
    int nl = threadIdx.x / C;
    int i = blockIdx.x * NPB + nl;
    if (i >= n) return;
    int k = base[i];
    int kend = k + cnt[i];
    float di = dinv[i];
    const float4* X4 = reinterpret_cast<const float4*>(xin);
    float4 acc = {0.f, 0.f, 0.f, 0.f};
    float4 acc2 = {0.f, 0.f, 0.f, 0.f};
    for (; k + 1 < kend; k += 2) {
        int2 ea = csr_sw[k];
        int2 eb = csr_sw[k + 1];
        float wa = __int_as_float(ea.y);
        float wb = __int_as_float(eb.y);
        float4 xa = X4[(long)ea.x * C + lane];
        float4 xb = X4[(long)eb.x * C + lane];
        acc.x += wa * xa.x; acc.y += wa * xa.y; acc.z += wa * xa.z; acc.w += wa * xa.w;
        acc2.x += wb * xb.x; acc2.y += wb * xb.y; acc2.z += wb * xb.z; acc2.w += wb * xb.w;
    }
    if (k < kend) {
        int2 ea = csr_sw[k];
        float wa = __int_as_float(ea.y);
        float4 xa = X4[(long)ea.x * C + lane];
        acc.x += wa * xa.x; acc.y += wa * xa.y; acc.z += wa * xa.z; acc.w += wa * xa.w;
    }
    acc.x += acc2.x; acc.y += acc2.y; acc.z += acc2.z; acc.w += acc2.w;
    float4 xs = X4[(long)i * C + lane];
    float4 o;
    o.x = di * (acc.x + di * xs.x);
    o.y = di * (acc.y + di * xs.y);
    o.z = di * (acc.z + di * xs.z);
    o.w = di * (acc.w + di * xs.w);
    if (L1EPI) {
        float4 bb = reinterpret_cast<const float4*>(b)[lane];
        float4 gg = reinterpret_cast<const float4*>(g)[lane];
        float4 ee = reinterpret_cast<const float4*>(be)[lane];
        float4 mm = reinterpret_cast<const float4*>(rm)[lane];
        float4 vv = reinterpret_cast<const float4*>(rv)[lane];
        o.x = elu_f((o.x + bb.x - mm.x) * rsqrtf(vv.x + EPSF) * gg.x + ee.x);
        o.y = elu_f((o.y + bb.y - mm.y) * rsqrtf(vv.y + EPSF) * gg.y + ee.y);
        o.z = elu_f((o.z + bb.z - mm.z) * rsqrtf(vv.z + EPSF) * gg.z + ee.z);
        o.w = elu_f((o.w + bb.w - mm.w) * rsqrtf(vv.w + EPSF) * gg.w + ee.w);
    }
    reinterpret_cast<float4*>(out)[(long)i * C + lane] = o;
}

// scalar gather for layer 4 + final sigmoid(elu(.)) epilogue, writes d_out
__global__ __launch_bounds__(256) void k_gather1_final(const int* __restrict__ base, const int* __restrict__ cnt,
                                                       const int2* __restrict__ csr_sw,
                                                       const float* __restrict__ dinv, const float* __restrict__ y,
                                                       const float* __restrict__ b4, float* __restrict__ out, int n) {
    int i = blockIdx.x * 256 + threadIdx.x;
    if (i >= n) return;
    int k = base[i];
    int kend = k + cnt[i];
    float di = dinv[i];
    float acc = 0.f;
    for (; k < kend; ++k) {
        int2 ea = csr_sw[k];
        acc += __int_as_float(ea.y) * y[ea.x];
    }
    float v = di * (acc + di * y[i]) + b4[0];
    v = elu_f(v);
    out[i] = 1.f / (1.f + expf(-v));
}

// ---------------- register-tiled dense GEMM ----------------
// Thread: TR=4 rows x 4 fouts. W staged in LDS, one ds_read_b128 per k shared by 4 rows.
// __launch_bounds__(256,4): cap VGPR at 128 so >=4 waves/SIMD (R3 lesson: full unroll
// hoisted 256 floats of X loads -> 256 VGPR -> 10.9% occupancy -> latency-exposed).
// #pragma unroll 2 keeps only 2 k0-iterations of X loads in flight.
template<int DIN, int DOUT, bool BN, bool FUSE_DOT>
__global__ __launch_bounds__(256, 4) void k_gemm_rt(const float* __restrict__ X, const float* __restrict__ W,
                                                    const float* __restrict__ b, const float* __restrict__ g,
                                                    const float* __restrict__ be, const float* __restrict__ rm,
                                                    const float* __restrict__ rv, const float* __restrict__ W4,
                                                    float* __restrict__ Y, int n) {
    constexpr int TR = 4;
    constexpr int FL = DOUT / 4;       // fout-lane groups
    constexpr int RG = 256 / FL;       // row-groups per block
    constexpr int BR = RG * TR;        // rows per block
    __shared__ float Wl[DIN * DOUT];
    for (int idx = threadIdx.x; idx < DIN * DOUT; idx += 256) Wl[idx] = W[idx];
    __syncthreads();
    const int fl = threadIdx.x % FL;
    const int rg = threadIdx.x / FL;
    const int f0 = fl * 4;
    const long r0 = (long)blockIdx.x * BR + (long)rg * TR;

    float4 z; z.x = z.y = z.z = z.w = 0.f;
    float4 acc[TR];
    #pragma unroll
    for (int r = 0; r < TR; ++r) acc[r] = z;

    #pragma unroll 2
    for (int k0 = 0; k0 < DIN; k0 += 4) {
        float4 xv[TR];
        #pragma unroll
        for (int r = 0; r < TR; ++r) {
            long row = r0 + r;
            xv[r] = (row < n) ? *reinterpret_cast<const float4*>(X + row * DIN + k0) : z;
        }
        #pragma unroll
        for (int kk = 0; kk < 4; ++kk) {
            float4 w4 = *reinterpret_cast<const float4*>(&Wl[(k0 + kk) * DOUT + f0]);
            #pragma unroll
            for (int r = 0; r < TR; ++r) {
                float xs = (kk == 0) ? xv[r].x : (kk == 1) ? xv[r].y : (kk == 2) ? xv[r].z : xv[r].w;
                acc[r].x += xs * w4.x;
                acc[r].y += xs * w4.y;
                acc[r].z += xs * w4.z;
                acc[r].w += xs * w4.w;
            }
        }
    }

    float4 bias = z, scale = z, shift = z, w4d = z;
    if (BN) {
        bias = *reinterpret_cast<const float4*>(b + f0);
        float4 gg = *reinterpret_cast<const float4*>(g + f0);
        float4 ee = *reinterpret_cast<const float4*>(be + f0);
        float4 mm = *reinterpret_cast<const float4*>(rm + f0);
        float4 vv = *reinterpret_cast<const float4*>(rv + f0);
        scale.x = gg.x * rsqrtf(vv.x + EPSF); shift.x = ee.x - mm.x * scale.x;
        scale.y = gg.y * rsqrtf(vv.y + EPSF); shift.y = ee.y - mm.y * scale.y;
        scale.z = gg.z * rsqrtf(vv.z + EPSF); shift.z = ee.z - mm.z * scale.z;
        scale.w = gg.w * rsqrtf(vv.w + EPSF); shift.w = ee.w - mm.w * scale.w;
    }
    if (FUSE_DOT) w4d = *reinterpret_cast<const float4*>(W4 + f0);

    #pragma unroll
    for (int r = 0; r < TR; ++r) {
        long row = r0 + r;
        if (row >= n) continue;
        float4 v = acc[r];
        if (BN) {
            v.x = elu_f((v.x + bias.x) * scale.x + shift.x);
            v.y = elu_f((v.y + bias.y) * scale.y + shift.y);
            v.z = elu_f((v.z + bias.z) * scale.z + shift.z);
            v.w = elu_f((v.w + bias.w) * scale.w + shift.w);
        }
        if (FUSE_DOT) {
            float p = v.x * w4d.x + v.y * w4d.y + v.z * w4d.z + v.w * w4d.w;
            #pragma unroll
            for (int m = 1; m < FL; m <<= 1) p += __shfl_xor(p, m, 64);
            if (fl == 0) Y[row] = p;
        } else {
            *reinterpret_cast<float4*>(Y + row * DOUT + f0) = v;
        }
    }
}

// ---------------- launch ----------------

extern "C" void kernel_launch(void* const* d_in, const int* in_sizes, int n_in,
                              void* d_out, int out_size, void* d_ws, size_t ws_size,
                              hipStream_t stream) {
    const float* x   = (const float*)d_in[0];
    const int*   edg = (const int*)d_in[1];
    const float* W1 = (const float*)d_in[2];
    const float* b1 = (const float*)d_in[3];
    const float* W2 = (const float*)d_in[4];
    const float* b2 = (const float*)d_in[5];
    const float* W3 = (const float*)d_in[6];
    const float* b3 = (const float*)d_in[7];
    const float* W4 = (const float*)d_in[8];
    const float* b4 = (const float*)d_in[9];
    const float* g1  = (const float*)d_in[10];
    const float* be1 = (const float*)d_in[11];
    const float* rm1 = (const float*)d_in[12];
    const float* rv1 = (const float*)d_in[13];
    const float* g2  = (const float*)d_in[14];
    const float* be2 = (const float*)d_in[15];
    const float* rm2 = (const float*)d_in[16];
    const float* rv2 = (const float*)d_in[17];
    const float* g3  = (const float*)d_in[18];
    const float* be3 = (const float*)d_in[19];
    const float* rm3 = (const float*)d_in[20];
    const float* rv3 = (const float*)d_in[21];
    float* out = (float*)d_out;

    const int N = in_sizes[0] / 64;
    const int E = in_sizes[1] / 2;
    const int* src = edg;
    const int* dst = edg + E;
    const int NB_SCAN = (N + SCAN_B - 1) / SCAN_B;

    // workspace layout (all 16B-aligned by construction)
    int*   cnt     = (int*)d_ws;                    // N
    int*   fcnt    = cnt + N;                       // N
    int*   base    = fcnt + N;                      // N
    int*   bsum    = base + N;                      // 256
    int2*  csr_sw  = (int2*)(bsum + 256);           // E int2 (8B-aligned)
    float* dinv    = (float*)(csr_sw + E);          // N
    float* A       = dinv + N;                      // N*64 max
    float* B       = A + (size_t)N * 64;            // N*128 max... (N*64 used)

    auto nb = [](long total) { return (int)((total + 255) / 256); };

    // CSR build (per call: workspace re-poisoned every launch)
    k_zero<<<nb(N), 256, 0, stream>>>(cnt, N);
    k_count_x<<<2048, 256, 0, stream>>>(dst, cnt, E, N);
    k_scan1<<<NB_SCAN, 256, 0, stream>>>(cnt, base, bsum, dinv, N);
    k_scan2<<<1, 256, 0, stream>>>(bsum, NB_SCAN);
    k_scan3<<<nb(N), 256, 0, stream>>>(base, fcnt, bsum, N);
    k_fill_x<<<2048, 256, 0, stream>>>(src, dst, fcnt, dinv, csr_sw, E, N);

    // Layer 1 (64->32): GEMM, then gather-agg fused with bias+BN+ELU
    k_gemm_rt<64, 32, false, false><<<(N + 127) / 128, 256, 0, stream>>>(
        x, W1, nullptr, nullptr, nullptr, nullptr, nullptr, nullptr, A, N);
    k_gather<32, true><<<(N + 31) / 32, 256, 0, stream>>>(base, cnt, csr_sw, dinv, A,
                                                          b1, g1, be1, rm1, rv1, B, N);

    // Layer 2 (32->64): gather-agg first, then fused GEMM+bias+BN+ELU
    k_gather<32, false><<<(N + 31) / 32, 256, 0, stream>>>(base, cnt, csr_sw, dinv, B,
                                                           nullptr, nullptr, nullptr, nullptr, nullptr, A, N);
    k_gemm_rt<32, 64, true, false><<<(N + 63) / 64, 256, 0, stream>>>(
        A, W2, b2, g2, be2, rm2, rv2, nullptr, B, N);

    // Layer 3 (64->128): gather-agg, then fused GEMM+bias+BN+ELU+dot(W4) -> y in B
    k_gather<64, false><<<(N + 15) / 16, 256, 0, stream>>>(base, cnt, csr_sw, dinv, B,
                                                           nullptr, nullptr, nullptr, nullptr, nullptr, A, N);
    k_gemm_rt<64, 128, true, true><<<(N + 31) / 32, 256, 0, stream>>>(
        A, W3, b3, g3, be3, rm3, rv3, W4, B, N);

    // Layer 4 (128->1): scalar gather-agg fused with bias + sigmoid(elu(.)) -> d_out
    k_gather1_final<<<nb(N), 256, 0, stream>>>(base, cnt, csr_sw, dinv, B, b4, out, N);
}